// Round 12
// baseline (279.498 us; speedup 1.0000x reference)
//
#include <hip/hip_runtime.h>
#include <hip/hip_bf16.h>

// CrossScaleAttention on MI355X — round 21 (decisive attribution):
//   * Four gemm variants all land ~107-112us total-equivalent; occupancy
//     model refuted (r20 half-W: -1.8us). Two worlds remain: (A) proj still
//     ~90-110us, (B) proj ~55 and ~80us is dispatch-gap overhead.
//   * This round: split memset -> bin1 -> proj -> bin2 -> fusedA -> fusedB.
//     Fused halves (~53us each) lower the top-5 floor to ~53 so proj (and
//     bin1) surface WITH counters. One zero-risk tweak: gemm_q A-loads
//     hoisted before the W stage (overlap staging latency).
//   * Bodies otherwise byte-identical to r20 (265us best).

#define D 128
#define E1 4096    // edges per bin1 block (256 thr * 16)
#define BCAP 10240 // bucket capacity (mean 8192, sigma~90 -> 22 sigma slack)
#define LOG2E 1.44269504088896340736f

typedef __attribute__((ext_vector_type(8))) short bf16x8;
typedef __attribute__((ext_vector_type(4))) float f32x4;
typedef __attribute__((ext_vector_type(4))) int v4i;
typedef __attribute__((ext_vector_type(4))) unsigned v4u;

static __device__ __forceinline__ unsigned short f2bf(float f) {
  unsigned u = __float_as_uint(f);
  u += 0x7fff + ((u >> 16) & 1);  // RNE
  return (unsigned short)(u >> 16);
}
static __device__ __forceinline__ float bfl(unsigned u) {
  return __uint_as_float(u << 16);
}
static __device__ __forceinline__ float bfh(unsigned u) {
  return __uint_as_float(u & 0xffff0000u);
}

template <int CTRL>
static __device__ __forceinline__ float dpp_add(float x) {
  int y = __builtin_amdgcn_update_dpp(0, __float_as_int(x), CTRL, 0xF, 0xF, false);
  return x + __int_as_float(y);
}

static __device__ __forceinline__ float dot8(const float4& qa, const float4& qb,
                                             const v4u k0, const v4u k1) {
  return (qa.x * bfl(k0.x) + qa.y * bfh(k0.x) + qa.z * bfl(k0.y) +
          qa.w * bfh(k0.y)) +
         (qb.x * bfl(k1.x) + qb.y * bfh(k1.x) + qb.z * bfl(k1.y) +
          qb.w * bfh(k1.y));
}

// ---------------- W staging: global f32 -> LDS bf16, XOR-swizzled ------------
static __device__ __forceinline__ void stage_w(const float* __restrict__ W,
                                               char* lds) {
  const int tid = threadIdx.x;
#pragma unroll
  for (int i = 0; i < 8; ++i) {
    const int g = i * 256 + tid;
    const int r = g >> 4, c16 = g & 15;
    const float4 w0 = *(const float4*)(W + r * 128 + c16 * 8);
    const float4 w1 = *(const float4*)(W + r * 128 + c16 * 8 + 4);
    bf16x8 b;
    b[0] = f2bf(w0.x); b[1] = f2bf(w0.y); b[2] = f2bf(w0.z); b[3] = f2bf(w0.w);
    b[4] = f2bf(w1.x); b[5] = f2bf(w1.y); b[6] = f2bf(w1.z); b[7] = f2bf(w1.w);
    *(bf16x8*)(lds + r * 256 + (((c16 ^ (r & 7)) << 4))) = b;
  }
}

// Half stage (rows h*64 .. h*64+63 of W -> 16KB region, local rows 0..63).
static __device__ __forceinline__ void stage_w_half(const float* __restrict__ W,
                                                    char* lds, int h) {
  const int tid = threadIdx.x;
#pragma unroll
  for (int i = 0; i < 4; ++i) {
    const int g = i * 256 + tid;  // 1024 granules
    const int r = g >> 4, c16 = g & 15;
    const float* wp = W + (size_t)(h * 64 + r) * 128 + c16 * 8;
    const float4 w0 = *(const float4*)(wp);
    const float4 w1 = *(const float4*)(wp + 4);
    bf16x8 b;
    b[0] = f2bf(w0.x); b[1] = f2bf(w0.y); b[2] = f2bf(w0.z); b[3] = f2bf(w0.w);
    b[4] = f2bf(w1.x); b[5] = f2bf(w1.y); b[6] = f2bf(w1.z); b[7] = f2bf(w1.w);
    *(bf16x8*)(lds + r * 256 + (((c16 ^ (r & 7)) << 4))) = b;
  }
}

static __device__ __forceinline__ bf16x8 ldw_lds(const char* lds, int n,
                                                 int colbyte) {
  return *(const bf16x8*)(lds + n * 256 + (colbyte ^ ((n & 7) << 4)));
}

// ---------------- bin1 (r11 body) -------------------------------------------
static __device__ void bin1_body(
    int bx, int* h, int* basebuf, int* cur, const int* __restrict__ src_idx,
    const int* __restrict__ dst_idx, int* __restrict__ bins,
    int* __restrict__ bcount, int n) {
  const int tid = threadIdx.x;
  const int e0 = bx * E1;
  int dv[16], sv[16];
#pragma unroll
  for (int i = 0; i < 4; ++i) {
    int e = e0 + i * 1024 + tid * 4;
    if (e + 3 < n) {
      v4i d4 = __builtin_nontemporal_load((const v4i*)(dst_idx + e));
      v4i s4 = __builtin_nontemporal_load((const v4i*)(src_idx + e));
      dv[4 * i + 0] = d4.x; dv[4 * i + 1] = d4.y;
      dv[4 * i + 2] = d4.z; dv[4 * i + 3] = d4.w;
      sv[4 * i + 0] = s4.x; sv[4 * i + 1] = s4.y;
      sv[4 * i + 2] = s4.z; sv[4 * i + 3] = s4.w;
    } else {
      for (int k = 0; k < 4; ++k) {
        int ee = e + k;
        dv[4 * i + k] = (ee < n) ? dst_idx[ee] : -1;
        sv[4 * i + k] = (ee < n) ? src_idx[ee] : 0;
      }
    }
  }
  h[tid] = 0;
  __syncthreads();
#pragma unroll
  for (int i = 0; i < 16; ++i)
    if (dv[i] >= 0) atomicAdd(&h[dv[i] >> 8], 1);
  __syncthreads();
  const int c = h[tid];
  if (c > 0) basebuf[tid] = tid * BCAP + atomicAdd(&bcount[tid], c);
  cur[tid] = 0;
  __syncthreads();
#pragma unroll
  for (int i = 0; i < 16; ++i) {
    if (dv[i] >= 0) {
      const int b = dv[i] >> 8;
      const int r = atomicAdd(&cur[b], 1);
      const int off = basebuf[b] + r;
      if (off < (b + 1) * BCAP)  // 22-sigma guard vs OOB
        bins[off] = sv[i] | ((dv[i] & 255) << 17);
    }
  }
}

// ---------------- bin2: 1024-thread blocks (r18 body) ------------------------
static __device__ void bin2_body_1k(
    int b, int* smem, const int* __restrict__ bins,
    const int* __restrict__ bcount, int* __restrict__ csr,
    int* __restrict__ rowptr, int n_dst, int n_edges) {
  int* h = smem;
  int* ofs = smem + 256;
  int* cur = smem + 512;
  int* red = smem + 768;
  const int tid = threadIdx.x;

  if (tid < 256) red[tid] = (tid < b) ? min(bcount[tid], BCAP) : 0;
  __syncthreads();
  for (int off = 128; off > 0; off >>= 1) {
    if (tid < off) red[tid] += red[tid + off];
    __syncthreads();
  }
  const int gbase = red[0];
  const int cnt = min(bcount[b], BCAP);
  if (tid < 256) h[tid] = 0;
  __syncthreads();

  const int* bb = bins + b * BCAP;
  for (int i = tid; i < cnt; i += 1024) atomicAdd(&h[(bb[i] >> 17) & 255], 1);
  __syncthreads();

  const int myh = (tid < 256) ? h[tid] : 0;
  if (tid < 256) red[tid] = myh;
  __syncthreads();
  for (int off = 1; off < 256; off <<= 1) {
    int t = (tid >= off && tid < 256) ? red[tid - off] : 0;
    __syncthreads();
    if (tid < 256) red[tid] += t;
    __syncthreads();
  }
  if (tid < 256) {
    ofs[tid] = red[tid] - myh;
    cur[tid] = 0;
    const int d = b * 256 + tid;
    if (d < n_dst) rowptr[d] = gbase + ofs[tid];
    if (b == 0 && tid == 0) rowptr[n_dst] = n_edges;
  }
  __syncthreads();

  for (int i = tid; i < cnt; i += 1024) {
    const int p = bb[i];
    const int j = (p >> 17) & 255;
    const int r = atomicAdd(&cur[j], 1);
    csr[gbase + ofs[j] + r] = p & 0x1ffff;
  }
}

// ---------------- gemm_q (A-loads hoisted before W stage) --------------------
static __device__ void gemm_q_body(
    int bx, char* wlds, const float* __restrict__ X,
    const float* __restrict__ Wf, const float* __restrict__ bias,
    float* __restrict__ out, int N) {
  const int lane = threadIdx.x & 63;
  const int l15 = lane & 15, quad = lane >> 4;
  const int row0 = bx * 64 + (threadIdx.x >> 6) * 16;

  // A loads issued BEFORE staging (overlap staging latency)
  int ar = row0 + l15;
  if (ar >= N) ar = N - 1;
  const float* ap = X + (size_t)ar * D + quad * 8;
  float4 a0v[4], a1v[4];
#pragma unroll
  for (int kc = 0; kc < 4; ++kc) {
    a0v[kc] = *(const float4*)(ap + kc * 32);
    a1v[kc] = *(const float4*)(ap + kc * 32 + 4);
  }

  stage_w(Wf, wlds);
  __syncthreads();

  f32x4 acc[8];
#pragma unroll
  for (int t = 0; t < 8; ++t) acc[t] = (f32x4){0.f, 0.f, 0.f, 0.f};

#pragma unroll
  for (int kc = 0; kc < 4; ++kc) {
    bf16x8 a;
    a[0] = f2bf(a0v[kc].x); a[1] = f2bf(a0v[kc].y);
    a[2] = f2bf(a0v[kc].z); a[3] = f2bf(a0v[kc].w);
    a[4] = f2bf(a1v[kc].x); a[5] = f2bf(a1v[kc].y);
    a[6] = f2bf(a1v[kc].z); a[7] = f2bf(a1v[kc].w);
    const int cb = kc * 64 + quad * 16;
#pragma unroll
    for (int t = 0; t < 8; ++t) {
      bf16x8 b = ldw_lds(wlds, t * 16 + l15, cb);
      acc[t] = __builtin_amdgcn_mfma_f32_16x16x32_bf16(a, b, acc[t], 0, 0, 0);
    }
  }
#pragma unroll
  for (int t = 0; t < 8; ++t) {
    const int c = t * 16 + l15;
    const float bc = bias[c];
#pragma unroll
    for (int r = 0; r < 4; ++r) {
      const int row = row0 + quad * 4 + r;
      if (row < N) out[(size_t)row * D + c] = acc[t][r] + bc;
    }
  }
}

// ---------------- gemm_kv: half-W staging, 32KB total (r20 body) -------------
static __device__ void gemm_kv_body(
    int bx, char* wlds, const float* __restrict__ X,
    const float* __restrict__ Wkf, const float* __restrict__ bk,
    const float* __restrict__ Wvf, const float* __restrict__ bv,
    unsigned short* __restrict__ KV, int N) {
  char* wk = wlds;           // 16KB: current half of Wk
  char* wv = wlds + 16384;   // 16KB: current half of Wv
  const int tid = threadIdx.x;
  const int lane = tid & 63;
  const int l15 = lane & 15, quad = lane >> 4;
  const int wave = tid >> 6;
  const int row0 = bx * 64 + wave * 16;

  // A fragments: loaded+converted once, reused across both W halves.
  int ar = row0 + l15;
  if (ar >= N) ar = N - 1;
  const float* ap = X + (size_t)ar * D + quad * 8;
  bf16x8 afrag[4];
#pragma unroll
  for (int kc = 0; kc < 4; ++kc) {
    float4 a0 = *(const float4*)(ap + kc * 32);
    float4 a1 = *(const float4*)(ap + kc * 32 + 4);
    afrag[kc][0] = f2bf(a0.x); afrag[kc][1] = f2bf(a0.y);
    afrag[kc][2] = f2bf(a0.z); afrag[kc][3] = f2bf(a0.w);
    afrag[kc][4] = f2bf(a1.x); afrag[kc][5] = f2bf(a1.y);
    afrag[kc][6] = f2bf(a1.z); afrag[kc][7] = f2bf(a1.w);
  }

  f32x4 accK[8], accV[8];
#pragma unroll
  for (int t = 0; t < 8; ++t) {
    accK[t] = (f32x4){0.f, 0.f, 0.f, 0.f};
    accV[t] = (f32x4){0.f, 0.f, 0.f, 0.f};
  }

#pragma unroll
  for (int h = 0; h < 2; ++h) {
    __syncthreads();  // prior half's reads complete before overwrite
    stage_w_half(Wkf, wk, h);
    stage_w_half(Wvf, wv, h);
    __syncthreads();
#pragma unroll
    for (int kc = 0; kc < 4; ++kc) {
      const int cb = kc * 64 + quad * 16;
#pragma unroll
      for (int t = 0; t < 4; ++t) {
        const int n = t * 16 + l15;  // local row in the 64-row half
        bf16x8 b0 = ldw_lds(wk, n, cb);
        bf16x8 b1 = ldw_lds(wv, n, cb);
        accK[h * 4 + t] =
            __builtin_amdgcn_mfma_f32_16x16x32_bf16(afrag[kc], b0,
                                                    accK[h * 4 + t], 0, 0, 0);
        accV[h * 4 + t] =
            __builtin_amdgcn_mfma_f32_16x16x32_bf16(afrag[kc], b1,
                                                    accV[h * 4 + t], 0, 0, 0);
      }
    }
  }

  // interleave via the same 32KB region (64 rows x 256 ushort)
  __syncthreads();
  unsigned short (*stage)[256] = (unsigned short(*)[256])wlds;
#pragma unroll
  for (int t = 0; t < 8; ++t) {
    const int c = t * 16 + l15;
    const float bkc = bk[c], bvc = bv[c];
    const int ki = ((c >> 2) << 3) + (c & 3);
#pragma unroll
    for (int r = 0; r < 4; ++r) {
      const int lr = wave * 16 + quad * 4 + r;
      stage[lr][ki] = f2bf(accK[t][r] + bkc);
      stage[lr][ki + 4] = f2bf(accV[t][r] + bvc);
    }
  }
  __syncthreads();
  const int row_base = bx * 64;
#pragma unroll
  for (int i = 0; i < 8; ++i) {
    int idx = i * 256 + tid;
    int lr = idx >> 5;
    int c8 = (idx & 31) << 3;
    int grow = row_base + lr;
    if (grow < N)
      *(f32x4*)(KV + (size_t)grow * 256 + c8) = *(const f32x4*)&stage[lr][c8];
  }
}

// ---------------- fused body (r12, best measured) ----------------------------
static __device__ void fused_body(
    int v, const float* __restrict__ Q, const unsigned short* __restrict__ KV,
    const int* __restrict__ csr, const int* __restrict__ rowptr,
    float* __restrict__ out, int n_dst) {
  const int lane = threadIdx.x & 63;
  const int g = lane >> 4;   // edge group 0..3
  const int gl = lane & 15;  // lane within group
  int d = v * 4 + (threadIdx.x >> 6);
  if (d >= n_dst) return;
  d = __builtin_amdgcn_readfirstlane(d);
  const int start = __builtin_amdgcn_readfirstlane(rowptr[d]);
  const int n = __builtin_amdgcn_readfirstlane(rowptr[d + 1]) - start;

  const float qs = 0.25f * LOG2E;
  float4 q0 = *(const float4*)(Q + (size_t)d * D + 4 * gl);
  float4 q1 = *(const float4*)(Q + (size_t)d * D + 64 + 4 * gl);
  q0.x *= qs; q0.y *= qs; q0.z *= qs; q0.w *= qs;
  q1.x *= qs; q1.y *= qs; q1.z *= qs; q1.w *= qs;

  f32x4 acc0 = (f32x4){0.f, 0.f, 0.f, 0.f};
  f32x4 acc1 = (f32x4){0.f, 0.f, 0.f, 0.f};
  float den = 0.f;
  const int* cp = csr + start;

  for (int base = 0; base < n; base += 64) {
    const int il = base + lane;
    const int iv = __builtin_nontemporal_load(cp + ((il < n) ? il : (n - 1)));
    const int m = min(64, n - base);
    for (int j = 0; j < m; j += 16) {
      const int s0 = __shfl(iv, j + g, 64);
      const int s1 = __shfl(iv, j + 4 + g, 64);
      const int s2 = __shfl(iv, j + 8 + g, 64);
      const int s3 = __shfl(iv, j + 12 + g, 64);
      const unsigned short* r0 = KV + (size_t)s0 * 256 + gl * 8;
      const unsigned short* r1 = KV + (size_t)s1 * 256 + gl * 8;
      const unsigned short* r2 = KV + (size_t)s2 * 256 + gl * 8;
      const unsigned short* r3 = KV + (size_t)s3 * 256 + gl * 8;
      const v4u a0 = *(const v4u*)(r0);
      const v4u a1 = *(const v4u*)(r0 + 128);
      const v4u b0 = *(const v4u*)(r1);
      const v4u b1 = *(const v4u*)(r1 + 128);
      const v4u c0 = *(const v4u*)(r2);
      const v4u c1 = *(const v4u*)(r2 + 128);
      const v4u e0 = *(const v4u*)(r3);
      const v4u e1 = *(const v4u*)(r3 + 128);

      float p0 = dot8(q0, q1, a0, a1);
      float p1 = dot8(q0, q1, b0, b1);
      float p2 = dot8(q0, q1, c0, c1);
      float p3 = dot8(q0, q1, e0, e1);

      p0 = dpp_add<0xB1>(p0);  p1 = dpp_add<0xB1>(p1);
      p2 = dpp_add<0xB1>(p2);  p3 = dpp_add<0xB1>(p3);
      p0 = dpp_add<0x4E>(p0);  p1 = dpp_add<0x4E>(p1);
      p2 = dpp_add<0x4E>(p2);  p3 = dpp_add<0x4E>(p3);
      p0 = dpp_add<0x141>(p0); p1 = dpp_add<0x141>(p1);
      p2 = dpp_add<0x141>(p2); p3 = dpp_add<0x141>(p3);
      p0 = dpp_add<0x140>(p0); p1 = dpp_add<0x140>(p1);
      p2 = dpp_add<0x140>(p2); p3 = dpp_add<0x140>(p3);

      const float w0 = (j + g < m)      ? exp2f(p0) : 0.f;
      const float w1 = (j + 4 + g < m)  ? exp2f(p1) : 0.f;
      const float w2 = (j + 8 + g < m)  ? exp2f(p2) : 0.f;
      const float w3 = (j + 12 + g < m) ? exp2f(p3) : 0.f;

      acc0[0] += w0 * bfl(a0.z) + w1 * bfl(b0.z) + w2 * bfl(c0.z) + w3 * bfl(e0.z);
      acc0[1] += w0 * bfh(a0.z) + w1 * bfh(b0.z) + w2 * bfh(c0.z) + w3 * bfh(e0.z);
      acc0[2] += w0 * bfl(a0.w) + w1 * bfl(b0.w) + w2 * bfl(c0.w) + w3 * bfl(e0.w);
      acc0[3] += w0 * bfh(a0.w) + w1 * bfh(b0.w) + w2 * bfh(c0.w) + w3 * bfh(e0.w);
      acc1[0] += w0 * bfl(a1.z) + w1 * bfl(b1.z) + w2 * bfl(c1.z) + w3 * bfl(e1.z);
      acc1[1] += w0 * bfh(a1.z) + w1 * bfh(b1.z) + w2 * bfh(c1.z) + w3 * bfh(e1.z);
      acc1[2] += w0 * bfl(a1.w) + w1 * bfl(b1.w) + w2 * bfl(c1.w) + w3 * bfl(e1.w);
      acc1[3] += w0 * bfh(a1.w) + w1 * bfh(b1.w) + w2 * bfh(c1.w) + w3 * bfh(e1.w);
      den += (w0 + w1) + (w2 + w3);
    }
  }

#pragma unroll
  for (int msk = 16; msk <= 32; msk <<= 1) {
    acc0[0] += __shfl_xor(acc0[0], msk, 64);
    acc0[1] += __shfl_xor(acc0[1], msk, 64);
    acc0[2] += __shfl_xor(acc0[2], msk, 64);
    acc0[3] += __shfl_xor(acc0[3], msk, 64);
    acc1[0] += __shfl_xor(acc1[0], msk, 64);
    acc1[1] += __shfl_xor(acc1[1], msk, 64);
    acc1[2] += __shfl_xor(acc1[2], msk, 64);
    acc1[3] += __shfl_xor(acc1[3], msk, 64);
    den += __shfl_xor(den, msk, 64);
  }

  if (lane < 16) {
    const float r = (n > 0) ? 1.0f / den : 0.f;
    f32x4 o0 = (f32x4){acc0[0] * r, acc0[1] * r, acc0[2] * r, acc0[3] * r};
    f32x4 o1 = (f32x4){acc1[0] * r, acc1[1] * r, acc1[2] * r, acc1[3] * r};
    __builtin_nontemporal_store(o0, (f32x4*)(out + (size_t)d * D + 4 * gl));
    __builtin_nontemporal_store(o1,
                                (f32x4*)(out + (size_t)d * D + 64 + 4 * gl));
  }
}

// ---------------- kernels ----------------------------------------------------

__global__ __launch_bounds__(256) void bin1_kernel(
    const int* __restrict__ src_idx, const int* __restrict__ dst_idx,
    int* __restrict__ bins, int* __restrict__ bcount, int n_edges) {
  __shared__ int sh[768];
  bin1_body(blockIdx.x, sh, sh + 256, sh + 512, src_idx, dst_idx, bins, bcount,
            n_edges);
}

__global__ __launch_bounds__(256) void proj_kernel(
    const float* __restrict__ dst_feat, const float* __restrict__ Wq,
    const float* __restrict__ bq, float* __restrict__ Q, int n_dst,
    const float* __restrict__ src_feat, const float* __restrict__ Wk,
    const float* __restrict__ bk, const float* __restrict__ Wv,
    const float* __restrict__ bv, unsigned short* __restrict__ KV, int n_src,
    int gq) {
  __shared__ char wlds[32768];
  const int b = blockIdx.x;
  if (b < gq) {
    gemm_q_body(b, wlds, dst_feat, Wq, bq, Q, n_dst);
  } else {
    gemm_kv_body(b - gq, wlds, src_feat, Wk, bk, Wv, bv, KV, n_src);
  }
}

__global__ __launch_bounds__(1024) void bin2_kernel(
    const int* __restrict__ bins, const int* __restrict__ bcount,
    int* __restrict__ csr, int* __restrict__ rowptr, int n_dst, int n_edges) {
  __shared__ int sh[1024];
  bin2_body_1k(blockIdx.x, sh, bins, bcount, csr, rowptr, n_dst, n_edges);
}

__global__ __launch_bounds__(256) void fused_a_kernel(
    const float* __restrict__ Q, const unsigned short* __restrict__ KV,
    const int* __restrict__ csr, const int* __restrict__ rowptr,
    float* __restrict__ out, int n_dst, int voff) {
  fused_body(blockIdx.x + voff, Q, KV, csr, rowptr, out, n_dst);
}
__global__ __launch_bounds__(256) void fused_b_kernel(
    const float* __restrict__ Q, const unsigned short* __restrict__ KV,
    const int* __restrict__ csr, const int* __restrict__ rowptr,
    float* __restrict__ out, int n_dst, int voff) {
  fused_body(blockIdx.x + voff, Q, KV, csr, rowptr, out, n_dst);
}

extern "C" void kernel_launch(void* const* d_in, const int* in_sizes, int n_in,
                              void* d_out, int out_size, void* d_ws,
                              size_t ws_size, hipStream_t stream) {
  const float* src_feat = (const float*)d_in[0];
  const float* dst_feat = (const float*)d_in[1];
  const int* src_idx = (const int*)d_in[2];
  const int* dst_idx = (const int*)d_in[3];
  const float* Wq = (const float*)d_in[4];
  const float* bq = (const float*)d_in[5];
  const float* Wk = (const float*)d_in[6];
  const float* bk = (const float*)d_in[7];
  const float* Wv = (const float*)d_in[8];
  const float* bv = (const float*)d_in[9];

  const int n_src = in_sizes[0] / D;
  const int n_dst = in_sizes[1] / D;
  const int n_edges = in_sizes[2];
  const int nbk = (n_dst + 255) >> 8;  // coarse buckets (dst>>8)

  float* out = (float*)d_out;

  // Workspace: Q f32[n_dst*D] | KV bf16[n_src*256] |
  //            bcount int[256] | rowptr int[n_dst+1] | csr int[n_edges] |
  //            bins int[nbk*BCAP]
  float* Q = (float*)d_ws;
  unsigned short* KV = (unsigned short*)(Q + (size_t)n_dst * D);
  int* bcount = (int*)(KV + (size_t)n_src * 256);
  int* rowptr = bcount + 256;
  int* csr = rowptr + (n_dst + 1);
  int* bins = csr + n_edges;

  (void)hipMemsetAsync(bcount, 0, 256 * sizeof(int), stream);

  dim3 blk(256);
  const int g1 = (n_edges + E1 - 1) / E1;
  const int gq = (n_dst + 63) / 64;
  const int gkv = (n_src + 63) / 64;
  const int nf = (n_dst + 3) / 4;
  const int nfh = (nf + 1) / 2;

  // 1) bin1
  bin1_kernel<<<dim3(g1), blk, 0, stream>>>(src_idx, dst_idx, bins, bcount,
                                            n_edges);

  // 2) projections (measured separately this round)
  proj_kernel<<<dim3(gq + gkv), blk, 0, stream>>>(
      dst_feat, Wq, bq, Q, n_dst, src_feat, Wk, bk, Wv, bv, KV, n_src, gq);

  // 3) bin2 (1024-thread blocks)
  bin2_kernel<<<dim3(nbk), dim3(1024), 0, stream>>>(bins, bcount, csr, rowptr,
                                                    n_dst, n_edges);

  // 4) fused aggregation in two halves (visibility floor ~53us)
  fused_a_kernel<<<dim3(nfh), blk, 0, stream>>>(Q, KV, csr, rowptr, out, n_dst,
                                                0);
  fused_b_kernel<<<dim3(nf - nfh), blk, 0, stream>>>(Q, KV, csr, rowptr, out,
                                                     n_dst, nfh);
}

// Round 13
// 258.527 us; speedup vs baseline: 1.0811x; 1.0811x over previous
//
#include <hip/hip_runtime.h>
#include <hip/hip_bf16.h>

// CrossScaleAttention on MI355X — round 22 (consolidate + fixed-cost test):
//   * r21 attribution: fused 106 | proj 61 | bin1 ~40 | bin2 ~23 | gaps ~9 ea.
//     Merging latency-bound phases does NOT overlap work (work-conserving);
//     it only saves the boundary. Proj shows ~10-20us per-block fixed cost.
//   * This round: memset -> front{bin1||proj} -> bin2 -> fused (r20 shape,
//     saves 2 gaps vs r21) + gemm_q does 2 row-tiles per W stage (782->391
//     blocks, 32KB LDS unchanged) — clean test of the per-block fixed cost.
//   * Bodies otherwise r20/r21 proven set (hoisted-A, half-W kv, 1024t bin2).

#define D 128
#define E1 4096    // edges per bin1 block (256 thr * 16)
#define BCAP 10240 // bucket capacity (mean 8192, sigma~90 -> 22 sigma slack)
#define LOG2E 1.44269504088896340736f

typedef __attribute__((ext_vector_type(8))) short bf16x8;
typedef __attribute__((ext_vector_type(4))) float f32x4;
typedef __attribute__((ext_vector_type(4))) int v4i;
typedef __attribute__((ext_vector_type(4))) unsigned v4u;

static __device__ __forceinline__ unsigned short f2bf(float f) {
  unsigned u = __float_as_uint(f);
  u += 0x7fff + ((u >> 16) & 1);  // RNE
  return (unsigned short)(u >> 16);
}
static __device__ __forceinline__ float bfl(unsigned u) {
  return __uint_as_float(u << 16);
}
static __device__ __forceinline__ float bfh(unsigned u) {
  return __uint_as_float(u & 0xffff0000u);
}

template <int CTRL>
static __device__ __forceinline__ float dpp_add(float x) {
  int y = __builtin_amdgcn_update_dpp(0, __float_as_int(x), CTRL, 0xF, 0xF, false);
  return x + __int_as_float(y);
}

static __device__ __forceinline__ float dot8(const float4& qa, const float4& qb,
                                             const v4u k0, const v4u k1) {
  return (qa.x * bfl(k0.x) + qa.y * bfh(k0.x) + qa.z * bfl(k0.y) +
          qa.w * bfh(k0.y)) +
         (qb.x * bfl(k1.x) + qb.y * bfh(k1.x) + qb.z * bfl(k1.y) +
          qb.w * bfh(k1.y));
}

// ---------------- W staging: global f32 -> LDS bf16, XOR-swizzled ------------
static __device__ __forceinline__ void stage_w(const float* __restrict__ W,
                                               char* lds) {
  const int tid = threadIdx.x;
#pragma unroll
  for (int i = 0; i < 8; ++i) {
    const int g = i * 256 + tid;
    const int r = g >> 4, c16 = g & 15;
    const float4 w0 = *(const float4*)(W + r * 128 + c16 * 8);
    const float4 w1 = *(const float4*)(W + r * 128 + c16 * 8 + 4);
    bf16x8 b;
    b[0] = f2bf(w0.x); b[1] = f2bf(w0.y); b[2] = f2bf(w0.z); b[3] = f2bf(w0.w);
    b[4] = f2bf(w1.x); b[5] = f2bf(w1.y); b[6] = f2bf(w1.z); b[7] = f2bf(w1.w);
    *(bf16x8*)(lds + r * 256 + (((c16 ^ (r & 7)) << 4))) = b;
  }
}

// Half stage (rows h*64 .. h*64+63 of W -> 16KB region, local rows 0..63).
static __device__ __forceinline__ void stage_w_half(const float* __restrict__ W,
                                                    char* lds, int h) {
  const int tid = threadIdx.x;
#pragma unroll
  for (int i = 0; i < 4; ++i) {
    const int g = i * 256 + tid;  // 1024 granules
    const int r = g >> 4, c16 = g & 15;
    const float* wp = W + (size_t)(h * 64 + r) * 128 + c16 * 8;
    const float4 w0 = *(const float4*)(wp);
    const float4 w1 = *(const float4*)(wp + 4);
    bf16x8 b;
    b[0] = f2bf(w0.x); b[1] = f2bf(w0.y); b[2] = f2bf(w0.z); b[3] = f2bf(w0.w);
    b[4] = f2bf(w1.x); b[5] = f2bf(w1.y); b[6] = f2bf(w1.z); b[7] = f2bf(w1.w);
    *(bf16x8*)(lds + r * 256 + (((c16 ^ (r & 7)) << 4))) = b;
  }
}

static __device__ __forceinline__ bf16x8 ldw_lds(const char* lds, int n,
                                                 int colbyte) {
  return *(const bf16x8*)(lds + n * 256 + (colbyte ^ ((n & 7) << 4)));
}

// ---------------- bin1 (r11 body) -------------------------------------------
static __device__ void bin1_body(
    int bx, int* h, int* basebuf, int* cur, const int* __restrict__ src_idx,
    const int* __restrict__ dst_idx, int* __restrict__ bins,
    int* __restrict__ bcount, int n) {
  const int tid = threadIdx.x;
  const int e0 = bx * E1;
  int dv[16], sv[16];
#pragma unroll
  for (int i = 0; i < 4; ++i) {
    int e = e0 + i * 1024 + tid * 4;
    if (e + 3 < n) {
      v4i d4 = __builtin_nontemporal_load((const v4i*)(dst_idx + e));
      v4i s4 = __builtin_nontemporal_load((const v4i*)(src_idx + e));
      dv[4 * i + 0] = d4.x; dv[4 * i + 1] = d4.y;
      dv[4 * i + 2] = d4.z; dv[4 * i + 3] = d4.w;
      sv[4 * i + 0] = s4.x; sv[4 * i + 1] = s4.y;
      sv[4 * i + 2] = s4.z; sv[4 * i + 3] = s4.w;
    } else {
      for (int k = 0; k < 4; ++k) {
        int ee = e + k;
        dv[4 * i + k] = (ee < n) ? dst_idx[ee] : -1;
        sv[4 * i + k] = (ee < n) ? src_idx[ee] : 0;
      }
    }
  }
  h[tid] = 0;
  __syncthreads();
#pragma unroll
  for (int i = 0; i < 16; ++i)
    if (dv[i] >= 0) atomicAdd(&h[dv[i] >> 8], 1);
  __syncthreads();
  const int c = h[tid];
  if (c > 0) basebuf[tid] = tid * BCAP + atomicAdd(&bcount[tid], c);
  cur[tid] = 0;
  __syncthreads();
#pragma unroll
  for (int i = 0; i < 16; ++i) {
    if (dv[i] >= 0) {
      const int b = dv[i] >> 8;
      const int r = atomicAdd(&cur[b], 1);
      const int off = basebuf[b] + r;
      if (off < (b + 1) * BCAP)  // 22-sigma guard vs OOB
        bins[off] = sv[i] | ((dv[i] & 255) << 17);
    }
  }
}

// ---------------- bin2: 1024-thread blocks (r18 body) ------------------------
static __device__ void bin2_body_1k(
    int b, int* smem, const int* __restrict__ bins,
    const int* __restrict__ bcount, int* __restrict__ csr,
    int* __restrict__ rowptr, int n_dst, int n_edges) {
  int* h = smem;
  int* ofs = smem + 256;
  int* cur = smem + 512;
  int* red = smem + 768;
  const int tid = threadIdx.x;

  if (tid < 256) red[tid] = (tid < b) ? min(bcount[tid], BCAP) : 0;
  __syncthreads();
  for (int off = 128; off > 0; off >>= 1) {
    if (tid < off) red[tid] += red[tid + off];
    __syncthreads();
  }
  const int gbase = red[0];
  const int cnt = min(bcount[b], BCAP);
  if (tid < 256) h[tid] = 0;
  __syncthreads();

  const int* bb = bins + b * BCAP;
  for (int i = tid; i < cnt; i += 1024) atomicAdd(&h[(bb[i] >> 17) & 255], 1);
  __syncthreads();

  const int myh = (tid < 256) ? h[tid] : 0;
  if (tid < 256) red[tid] = myh;
  __syncthreads();
  for (int off = 1; off < 256; off <<= 1) {
    int t = (tid >= off && tid < 256) ? red[tid - off] : 0;
    __syncthreads();
    if (tid < 256) red[tid] += t;
    __syncthreads();
  }
  if (tid < 256) {
    ofs[tid] = red[tid] - myh;
    cur[tid] = 0;
    const int d = b * 256 + tid;
    if (d < n_dst) rowptr[d] = gbase + ofs[tid];
    if (b == 0 && tid == 0) rowptr[n_dst] = n_edges;
  }
  __syncthreads();

  for (int i = tid; i < cnt; i += 1024) {
    const int p = bb[i];
    const int j = (p >> 17) & 255;
    const int r = atomicAdd(&cur[j], 1);
    csr[gbase + ofs[j] + r] = p & 0x1ffff;
  }
}

// ---------------- gemm_q: 2 row-tiles per W stage ----------------------------
static __device__ void gemm_q_body(
    int bx, char* wlds, const float* __restrict__ X,
    const float* __restrict__ Wf, const float* __restrict__ bias,
    float* __restrict__ out, int N) {
  const int lane = threadIdx.x & 63;
  const int l15 = lane & 15, quad = lane >> 4;
  const int wave = threadIdx.x >> 6;

  // chunk-0 A loads issued BEFORE staging (overlap staging latency)
  int ar0 = bx * 128 + wave * 16 + l15;
  if (ar0 >= N) ar0 = N - 1;
  const float* ap0 = X + (size_t)ar0 * D + quad * 8;
  float4 p0[4], p1[4];
#pragma unroll
  for (int kc = 0; kc < 4; ++kc) {
    p0[kc] = *(const float4*)(ap0 + kc * 32);
    p1[kc] = *(const float4*)(ap0 + kc * 32 + 4);
  }

  stage_w(Wf, wlds);
  __syncthreads();

#pragma unroll
  for (int ch = 0; ch < 2; ++ch) {
    const int row0 = bx * 128 + ch * 64 + wave * 16;
    if (ch == 1) {
      int ar = row0 + l15;
      if (ar >= N) ar = N - 1;
      const float* ap = X + (size_t)ar * D + quad * 8;
#pragma unroll
      for (int kc = 0; kc < 4; ++kc) {
        p0[kc] = *(const float4*)(ap + kc * 32);
        p1[kc] = *(const float4*)(ap + kc * 32 + 4);
      }
    }

    f32x4 acc[8];
#pragma unroll
    for (int t = 0; t < 8; ++t) acc[t] = (f32x4){0.f, 0.f, 0.f, 0.f};

#pragma unroll
    for (int kc = 0; kc < 4; ++kc) {
      bf16x8 a;
      a[0] = f2bf(p0[kc].x); a[1] = f2bf(p0[kc].y);
      a[2] = f2bf(p0[kc].z); a[3] = f2bf(p0[kc].w);
      a[4] = f2bf(p1[kc].x); a[5] = f2bf(p1[kc].y);
      a[6] = f2bf(p1[kc].z); a[7] = f2bf(p1[kc].w);
      const int cb = kc * 64 + quad * 16;
#pragma unroll
      for (int t = 0; t < 8; ++t) {
        bf16x8 b = ldw_lds(wlds, t * 16 + l15, cb);
        acc[t] = __builtin_amdgcn_mfma_f32_16x16x32_bf16(a, b, acc[t], 0, 0, 0);
      }
    }
#pragma unroll
    for (int t = 0; t < 8; ++t) {
      const int c = t * 16 + l15;
      const float bc = bias[c];
#pragma unroll
      for (int r = 0; r < 4; ++r) {
        const int row = row0 + quad * 4 + r;
        if (row < N) out[(size_t)row * D + c] = acc[t][r] + bc;
      }
    }
  }
}

// ---------------- gemm_kv: half-W staging, 32KB total (r20 body) -------------
static __device__ void gemm_kv_body(
    int bx, char* wlds, const float* __restrict__ X,
    const float* __restrict__ Wkf, const float* __restrict__ bk,
    const float* __restrict__ Wvf, const float* __restrict__ bv,
    unsigned short* __restrict__ KV, int N) {
  char* wk = wlds;           // 16KB: current half of Wk
  char* wv = wlds + 16384;   // 16KB: current half of Wv
  const int tid = threadIdx.x;
  const int lane = tid & 63;
  const int l15 = lane & 15, quad = lane >> 4;
  const int wave = tid >> 6;
  const int row0 = bx * 64 + wave * 16;

  // A fragments: loaded+converted once, reused across both W halves.
  int ar = row0 + l15;
  if (ar >= N) ar = N - 1;
  const float* ap = X + (size_t)ar * D + quad * 8;
  bf16x8 afrag[4];
#pragma unroll
  for (int kc = 0; kc < 4; ++kc) {
    float4 a0 = *(const float4*)(ap + kc * 32);
    float4 a1 = *(const float4*)(ap + kc * 32 + 4);
    afrag[kc][0] = f2bf(a0.x); afrag[kc][1] = f2bf(a0.y);
    afrag[kc][2] = f2bf(a0.z); afrag[kc][3] = f2bf(a0.w);
    afrag[kc][4] = f2bf(a1.x); afrag[kc][5] = f2bf(a1.y);
    afrag[kc][6] = f2bf(a1.z); afrag[kc][7] = f2bf(a1.w);
  }

  f32x4 accK[8], accV[8];
#pragma unroll
  for (int t = 0; t < 8; ++t) {
    accK[t] = (f32x4){0.f, 0.f, 0.f, 0.f};
    accV[t] = (f32x4){0.f, 0.f, 0.f, 0.f};
  }

#pragma unroll
  for (int h = 0; h < 2; ++h) {
    __syncthreads();  // prior half's reads complete before overwrite
    stage_w_half(Wkf, wk, h);
    stage_w_half(Wvf, wv, h);
    __syncthreads();
#pragma unroll
    for (int kc = 0; kc < 4; ++kc) {
      const int cb = kc * 64 + quad * 16;
#pragma unroll
      for (int t = 0; t < 4; ++t) {
        const int n = t * 16 + l15;  // local row in the 64-row half
        bf16x8 b0 = ldw_lds(wk, n, cb);
        bf16x8 b1 = ldw_lds(wv, n, cb);
        accK[h * 4 + t] =
            __builtin_amdgcn_mfma_f32_16x16x32_bf16(afrag[kc], b0,
                                                    accK[h * 4 + t], 0, 0, 0);
        accV[h * 4 + t] =
            __builtin_amdgcn_mfma_f32_16x16x32_bf16(afrag[kc], b1,
                                                    accV[h * 4 + t], 0, 0, 0);
      }
    }
  }

  // interleave via the same 32KB region (64 rows x 256 ushort)
  __syncthreads();
  unsigned short (*stage)[256] = (unsigned short(*)[256])wlds;
#pragma unroll
  for (int t = 0; t < 8; ++t) {
    const int c = t * 16 + l15;
    const float bkc = bk[c], bvc = bv[c];
    const int ki = ((c >> 2) << 3) + (c & 3);
#pragma unroll
    for (int r = 0; r < 4; ++r) {
      const int lr = wave * 16 + quad * 4 + r;
      stage[lr][ki] = f2bf(accK[t][r] + bkc);
      stage[lr][ki + 4] = f2bf(accV[t][r] + bvc);
    }
  }
  __syncthreads();
  const int row_base = bx * 64;
#pragma unroll
  for (int i = 0; i < 8; ++i) {
    int idx = i * 256 + tid;
    int lr = idx >> 5;
    int c8 = (idx & 31) << 3;
    int grow = row_base + lr;
    if (grow < N)
      *(f32x4*)(KV + (size_t)grow * 256 + c8) = *(const f32x4*)&stage[lr][c8];
  }
}

// ---------------- fused body (r12, best measured) ----------------------------
static __device__ void fused_body(
    int v, const float* __restrict__ Q, const unsigned short* __restrict__ KV,
    const int* __restrict__ csr, const int* __restrict__ rowptr,
    float* __restrict__ out, int n_dst) {
  const int lane = threadIdx.x & 63;
  const int g = lane >> 4;   // edge group 0..3
  const int gl = lane & 15;  // lane within group
  int d = v * 4 + (threadIdx.x >> 6);
  if (d >= n_dst) return;
  d = __builtin_amdgcn_readfirstlane(d);
  const int start = __builtin_amdgcn_readfirstlane(rowptr[d]);
  const int n = __builtin_amdgcn_readfirstlane(rowptr[d + 1]) - start;

  const float qs = 0.25f * LOG2E;
  float4 q0 = *(const float4*)(Q + (size_t)d * D + 4 * gl);
  float4 q1 = *(const float4*)(Q + (size_t)d * D + 64 + 4 * gl);
  q0.x *= qs; q0.y *= qs; q0.z *= qs; q0.w *= qs;
  q1.x *= qs; q1.y *= qs; q1.z *= qs; q1.w *= qs;

  f32x4 acc0 = (f32x4){0.f, 0.f, 0.f, 0.f};
  f32x4 acc1 = (f32x4){0.f, 0.f, 0.f, 0.f};
  float den = 0.f;
  const int* cp = csr + start;

  for (int base = 0; base < n; base += 64) {
    const int il = base + lane;
    const int iv = __builtin_nontemporal_load(cp + ((il < n) ? il : (n - 1)));
    const int m = min(64, n - base);
    for (int j = 0; j < m; j += 16) {
      const int s0 = __shfl(iv, j + g, 64);
      const int s1 = __shfl(iv, j + 4 + g, 64);
      const int s2 = __shfl(iv, j + 8 + g, 64);
      const int s3 = __shfl(iv, j + 12 + g, 64);
      const unsigned short* r0 = KV + (size_t)s0 * 256 + gl * 8;
      const unsigned short* r1 = KV + (size_t)s1 * 256 + gl * 8;
      const unsigned short* r2 = KV + (size_t)s2 * 256 + gl * 8;
      const unsigned short* r3 = KV + (size_t)s3 * 256 + gl * 8;
      const v4u a0 = *(const v4u*)(r0);
      const v4u a1 = *(const v4u*)(r0 + 128);
      const v4u b0 = *(const v4u*)(r1);
      const v4u b1 = *(const v4u*)(r1 + 128);
      const v4u c0 = *(const v4u*)(r2);
      const v4u c1 = *(const v4u*)(r2 + 128);
      const v4u e0 = *(const v4u*)(r3);
      const v4u e1 = *(const v4u*)(r3 + 128);

      float p0 = dot8(q0, q1, a0, a1);
      float p1 = dot8(q0, q1, b0, b1);
      float p2 = dot8(q0, q1, c0, c1);
      float p3 = dot8(q0, q1, e0, e1);

      p0 = dpp_add<0xB1>(p0);  p1 = dpp_add<0xB1>(p1);
      p2 = dpp_add<0xB1>(p2);  p3 = dpp_add<0xB1>(p3);
      p0 = dpp_add<0x4E>(p0);  p1 = dpp_add<0x4E>(p1);
      p2 = dpp_add<0x4E>(p2);  p3 = dpp_add<0x4E>(p3);
      p0 = dpp_add<0x141>(p0); p1 = dpp_add<0x141>(p1);
      p2 = dpp_add<0x141>(p2); p3 = dpp_add<0x141>(p3);
      p0 = dpp_add<0x140>(p0); p1 = dpp_add<0x140>(p1);
      p2 = dpp_add<0x140>(p2); p3 = dpp_add<0x140>(p3);

      const float w0 = (j + g < m)      ? exp2f(p0) : 0.f;
      const float w1 = (j + 4 + g < m)  ? exp2f(p1) : 0.f;
      const float w2 = (j + 8 + g < m)  ? exp2f(p2) : 0.f;
      const float w3 = (j + 12 + g < m) ? exp2f(p3) : 0.f;

      acc0[0] += w0 * bfl(a0.z) + w1 * bfl(b0.z) + w2 * bfl(c0.z) + w3 * bfl(e0.z);
      acc0[1] += w0 * bfh(a0.z) + w1 * bfh(b0.z) + w2 * bfh(c0.z) + w3 * bfh(e0.z);
      acc0[2] += w0 * bfl(a0.w) + w1 * bfl(b0.w) + w2 * bfl(c0.w) + w3 * bfl(e0.w);
      acc0[3] += w0 * bfh(a0.w) + w1 * bfh(b0.w) + w2 * bfh(c0.w) + w3 * bfh(e0.w);
      acc1[0] += w0 * bfl(a1.z) + w1 * bfl(b1.z) + w2 * bfl(c1.z) + w3 * bfl(e1.z);
      acc1[1] += w0 * bfh(a1.z) + w1 * bfh(b1.z) + w2 * bfh(c1.z) + w3 * bfh(e1.z);
      acc1[2] += w0 * bfl(a1.w) + w1 * bfl(b1.w) + w2 * bfl(c1.w) + w3 * bfl(e1.w);
      acc1[3] += w0 * bfh(a1.w) + w1 * bfh(b1.w) + w2 * bfh(c1.w) + w3 * bfh(e1.w);
      den += (w0 + w1) + (w2 + w3);
    }
  }

#pragma unroll
  for (int msk = 16; msk <= 32; msk <<= 1) {
    acc0[0] += __shfl_xor(acc0[0], msk, 64);
    acc0[1] += __shfl_xor(acc0[1], msk, 64);
    acc0[2] += __shfl_xor(acc0[2], msk, 64);
    acc0[3] += __shfl_xor(acc0[3], msk, 64);
    acc1[0] += __shfl_xor(acc1[0], msk, 64);
    acc1[1] += __shfl_xor(acc1[1], msk, 64);
    acc1[2] += __shfl_xor(acc1[2], msk, 64);
    acc1[3] += __shfl_xor(acc1[3], msk, 64);
    den += __shfl_xor(den, msk, 64);
  }

  if (lane < 16) {
    const float r = (n > 0) ? 1.0f / den : 0.f;
    f32x4 o0 = (f32x4){acc0[0] * r, acc0[1] * r, acc0[2] * r, acc0[3] * r};
    f32x4 o1 = (f32x4){acc1[0] * r, acc1[1] * r, acc1[2] * r, acc1[3] * r};
    __builtin_nontemporal_store(o0, (f32x4*)(out + (size_t)d * D + 4 * gl));
    __builtin_nontemporal_store(o1,
                                (f32x4*)(out + (size_t)d * D + 64 + 4 * gl));
  }
}

// ---------------- kernels ----------------------------------------------------

// front: [0,g1) bin1 | [g1,g1+gq2) gemm_q (128 rows) | rest gemm_kv. 32KB LDS.
__global__ __launch_bounds__(256) void front_kernel(
    const int* __restrict__ src_idx, const int* __restrict__ dst_idx,
    int* __restrict__ bins, int* __restrict__ bcount, int n_edges,
    const float* __restrict__ dst_feat, const float* __restrict__ Wq,
    const float* __restrict__ bq, float* __restrict__ Q, int n_dst,
    const float* __restrict__ src_feat, const float* __restrict__ Wk,
    const float* __restrict__ bk, const float* __restrict__ Wv,
    const float* __restrict__ bv, unsigned short* __restrict__ KV, int n_src,
    int g1, int gq2) {
  __shared__ char wlds[32768];
  const int b = blockIdx.x;
  if (b < g1) {
    int* sh = (int*)wlds;
    bin1_body(b, sh, sh + 256, sh + 512, src_idx, dst_idx, bins, bcount,
              n_edges);
  } else if (b < g1 + gq2) {
    gemm_q_body(b - g1, wlds, dst_feat, Wq, bq, Q, n_dst);
  } else {
    gemm_kv_body(b - g1 - gq2, wlds, src_feat, Wk, bk, Wv, bv, KV, n_src);
  }
}

__global__ __launch_bounds__(1024) void bin2_kernel(
    const int* __restrict__ bins, const int* __restrict__ bcount,
    int* __restrict__ csr, int* __restrict__ rowptr, int n_dst, int n_edges) {
  __shared__ int sh[1024];
  bin2_body_1k(blockIdx.x, sh, bins, bcount, csr, rowptr, n_dst, n_edges);
}

__global__ __launch_bounds__(256) void fused_agg_kernel(
    const float* __restrict__ Q, const unsigned short* __restrict__ KV,
    const int* __restrict__ csr, const int* __restrict__ rowptr,
    float* __restrict__ out, int n_dst) {
  fused_body(blockIdx.x, Q, KV, csr, rowptr, out, n_dst);
}

extern "C" void kernel_launch(void* const* d_in, const int* in_sizes, int n_in,
                              void* d_out, int out_size, void* d_ws,
                              size_t ws_size, hipStream_t stream) {
  const float* src_feat = (const float*)d_in[0];
  const float* dst_feat = (const float*)d_in[1];
  const int* src_idx = (const int*)d_in[2];
  const int* dst_idx = (const int*)d_in[3];
  const float* Wq = (const float*)d_in[4];
  const float* bq = (const float*)d_in[5];
  const float* Wk = (const float*)d_in[6];
  const float* bk = (const float*)d_in[7];
  const float* Wv = (const float*)d_in[8];
  const float* bv = (const float*)d_in[9];

  const int n_src = in_sizes[0] / D;
  const int n_dst = in_sizes[1] / D;
  const int n_edges = in_sizes[2];
  const int nbk = (n_dst + 255) >> 8;  // coarse buckets (dst>>8)

  float* out = (float*)d_out;

  // Workspace: Q f32[n_dst*D] | KV bf16[n_src*256] |
  //            bcount int[256] | rowptr int[n_dst+1] | csr int[n_edges] |
  //            bins int[nbk*BCAP]
  float* Q = (float*)d_ws;
  unsigned short* KV = (unsigned short*)(Q + (size_t)n_dst * D);
  int* bcount = (int*)(KV + (size_t)n_src * 256);
  int* rowptr = bcount + 256;
  int* csr = rowptr + (n_dst + 1);
  int* bins = csr + n_edges;

  (void)hipMemsetAsync(bcount, 0, 256 * sizeof(int), stream);

  dim3 blk(256);
  const int g1 = (n_edges + E1 - 1) / E1;
  const int gq2 = (n_dst + 127) / 128;
  const int gkv = (n_src + 63) / 64;
  const int nf = (n_dst + 3) / 4;

  // 1) front: {bin1 || gemm_q(2-tile) || gemm_kv}
  front_kernel<<<dim3(g1 + gq2 + gkv), blk, 0, stream>>>(
      src_idx, dst_idx, bins, bcount, n_edges, dst_feat, Wq, bq, Q, n_dst,
      src_feat, Wk, bk, Wv, bv, KV, n_src, g1, gq2);

  // 2) bin2 (1024-thread blocks)
  bin2_kernel<<<dim3(nbk), dim3(1024), 0, stream>>>(bins, bcount, csr, rowptr,
                                                    n_dst, n_edges);

  // 3) fused aggregation (single kernel, full grid)
  fused_agg_kernel<<<dim3(nf), blk, 0, stream>>>(Q, KV, csr, rowptr, out,
                                                 n_dst);
}